// Round 1
// baseline (364.191 us; speedup 1.0000x reference)
//
#include <hip/hip_runtime.h>
#include <stdint.h>

typedef unsigned int u32;
typedef unsigned long long u64;

#define HW (1024*1024)
#define NSLICE 16
#define BATCH 8
#define KTOP 500
#define CAP 8192u
#define POST_MAX 83

// workspace byte offsets
#define WS_CNT   0          // u32[16]
#define WS_FLAG  64         // u32[16]
#define WS_TC2   128        // u32[16]
#define WS_HIST  256        // u32[16*256] -> ends 16640
#define WS_CAND  32768      // uint2[16*8192] -> 1 MiB, ends 1081344
#define WS_S1    1081344    // uint2[16*512] -> ends 1146880
#define WS_SEL   1146880    // u32[8*512]   -> ends 1163264

// out layout (floats): boxes[0,36000) scores[36000,40000) clses[40000,44000)
// valid[44000,48000) keep[48000,52000)

// ---------------- K1: collect candidates (static threshold) + coarse hist ----
__global__ __launch_bounds__(256) void k1_collect(const float* __restrict__ heat,
                                                  u32* cnt, u32* ghist, uint2* cand){
  int s     = blockIdx.x >> 6;   // 16 slices x 64 chunks
  int chunk = blockIdx.x & 63;
  int tid   = threadIdx.x;
  __shared__ u32 lhist[256];
  lhist[tid] = 0;
  __syncthreads();
  const float4* hp = (const float4*)(heat + (size_t)s*HW + (size_t)chunk*16384);
  u32 hotcnt = 0;
  int lane = tid & 63;
  u32 base_pos = (u32)chunk * 16384u;
  for (int it = 0; it < 16; ++it){
    float4 v = hp[it*256 + tid];
    u32 idx0 = base_pos + (u32)(it*256 + tid)*4u;
    #pragma unroll
    for (int c = 0; c < 4; ++c){
      float val = (c==0)?v.x:(c==1)?v.y:(c==2)?v.z:v.w;
      u32 bits  = __float_as_uint(val);
      u32 delta = 0x3F800000u - bits;         // distance below 1.0 in ulps
      u32 bin   = delta >> 16;
      bool hot  = (bin >= 255u);              // clamp bin (covers v<~0.25, negatives)
      u64 m = __ballot(hot);
      hotcnt += (u32)__popcll(m);
      if (!hot) atomicAdd(&lhist[bin], 1u);
      if (delta < 17408u){                    // v > 1 - 17408*2^-24 ~ 0.998963
        u32 pos = atomicAdd(&cnt[s], 1u);
        if (pos < CAP) cand[(size_t)s*CAP + pos] = make_uint2(bits, idx0 + (u32)c);
      }
    }
  }
  if (lane == 0) atomicAdd(&lhist[255], hotcnt);
  __syncthreads();
  atomicAdd(&ghist[s*256 + tid], lhist[tid]);
}

// ---------------- K2: exactness check / fallback threshold ------------------
__global__ void k2_flags(u32* cnt, u32* flag, u32* tc2, const u32* __restrict__ ghist){
  int s = threadIdx.x;
  if (s >= NSLICE) return;
  u32 c = cnt[s];
  if (c >= (u32)KTOP){
    flag[s] = 1u; tc2[s] = 0u;
  } else {
    flag[s] = 0u; cnt[s] = 0u;
    u32 cum = 0; u32 b1 = 255u;
    for (u32 bb = 0; bb < 256u; ++bb){
      cum += ghist[s*256 + (int)bb];
      if (cum >= (u32)KTOP){ b1 = bb; break; }
    }
    tc2[s] = 0x3F800000u - ((b1 + 1u) << 16) + 1u;
  }
}

// ---------------- K3: fallback exact collect (normally empty) ---------------
__global__ __launch_bounds__(256) void k3_fallback(const float* __restrict__ heat,
                                                   u32* cnt, const u32* __restrict__ flag,
                                                   const u32* __restrict__ tc2, uint2* cand){
  int s = blockIdx.x >> 6;
  if (flag[s]) return;
  int chunk = blockIdx.x & 63;
  int tid = threadIdx.x;
  int t2 = (int)tc2[s];
  const float4* hp = (const float4*)(heat + (size_t)s*HW + (size_t)chunk*16384);
  u32 base_pos = (u32)chunk * 16384u;
  for (int it = 0; it < 16; ++it){
    float4 v = hp[it*256 + tid];
    u32 idx0 = base_pos + (u32)(it*256 + tid)*4u;
    #pragma unroll
    for (int c = 0; c < 4; ++c){
      float val = (c==0)?v.x:(c==1)?v.y:(c==2)?v.z:v.w;
      int bits = (int)__float_as_uint(val);   // signed cmp excludes negatives
      if (bits >= t2){
        u32 pos = atomicAdd(&cnt[s], 1u);
        if (pos < CAP) cand[(size_t)s*CAP + pos] = make_uint2((u32)bits, idx0 + (u32)c);
      }
    }
  }
}

// ---------------- bitonic sort (ascending, u64 keys in LDS) -----------------
__device__ inline void bitonic_sort(u64* key, int N, int tid, int nthr){
  for (int len = 2; len <= N; len <<= 1){
    for (int stride = len >> 1; stride > 0; stride >>= 1){
      __syncthreads();
      for (int i = tid; i < N; i += nthr){
        int j = i ^ stride;
        if (j > i){
          u64 a = key[i], b = key[j];
          bool up = ((i & len) == 0);
          if ((a > b) == up){ key[i] = b; key[j] = a; }
        }
      }
    }
  }
  __syncthreads();
}

// ---------------- K4: per-slice exact top-500 --------------------------------
__global__ __launch_bounds__(512) void k4_sort(const u32* __restrict__ cnt,
                                               const uint2* __restrict__ cand, uint2* s1){
  __shared__ u64 key[8192];   // 64 KiB
  int s = blockIdx.x, tid = threadIdx.x;
  u32 n = cnt[s]; if (n > CAP) n = CAP;
  int Np = 512; while (Np < (int)n) Np <<= 1;
  for (int i = tid; i < Np; i += 512){
    u64 k = ~0ull;
    if (i < (int)n){
      uint2 cv = cand[(size_t)s*CAP + i];
      k = ((u64)(~cv.x) << 32) | (u64)cv.y;   // value desc, index asc
    }
    key[i] = k;
  }
  bitonic_sort(key, Np, tid, 512);
  if (tid < KTOP){
    u64 k = key[tid];
    s1[s*512 + tid] = make_uint2(~(u32)(k >> 32), (u32)(k & 0xFFFFFFFFull));
  }
}

// ---------------- K5: per-batch merge of 2 classes (second top_k) ------------
__global__ __launch_bounds__(512) void k5_merge(const uint2* __restrict__ s1,
                                                u32* sel, float* out){
  __shared__ u64 key[1024];
  int b = blockIdx.x, tid = threadIdx.x;
  for (int i = tid; i < 1024; i += 512){
    u64 k = ~0ull;
    if (i < 2*KTOP){
      int c = (i >= KTOP) ? 1 : 0;
      int pos = i - c*KTOP;
      u32 bits = s1[(b*2 + c)*512 + pos].x;
      k = ((u64)(~bits) << 32) | (u64)i;      // tie-break: index in the c*K array
    }
    key[i] = k;
  }
  bitonic_sort(key, 1024, tid, 512);
  if (tid < KTOP){
    u64 k = key[tid];
    u32 src = (u32)(k & 0xFFFFFFFFull);
    int c = (src >= (u32)KTOP) ? 1 : 0;
    int pos = (int)src - c*KTOP;
    u32 bits = ~(u32)(k >> 32);
    sel[b*512 + tid] = s1[(b*2 + c)*512 + pos].y;
    out[36000 + b*KTOP + tid] = __uint_as_float(bits);
    out[40000 + b*KTOP + tid] = (float)c;
  }
}

// ---------------- K6: gather + decode + valid --------------------------------
__global__ __launch_bounds__(256) void k6_decode(const float* __restrict__ reg,
                                                 const float* __restrict__ rots,
                                                 const float* __restrict__ rotc,
                                                 const float* __restrict__ hei,
                                                 const float* __restrict__ dim,
                                                 const float* __restrict__ vel,
                                                 const u32* __restrict__ sel, float* out){
  int t = blockIdx.x*256 + threadIdx.x;
  if (t >= BATCH*KTOP) return;
  int b = t / KTOP, e = t % KTOP;
  u32 ind = sel[b*512 + e];
  float xs0 = (float)(ind & 1023u);
  float ys0 = (float)(ind >> 10);
  size_t bb = (size_t)b;
  float r0  = reg [(bb*2 + 0)*HW + ind];
  float r1  = reg [(bb*2 + 1)*HW + ind];
  float sn  = rots[ bb       *HW + ind];
  float cs  = rotc[ bb       *HW + ind];
  float he  = hei [ bb       *HW + ind];
  float d0  = dim [(bb*3 + 0)*HW + ind];
  float d1  = dim [(bb*3 + 1)*HW + ind];
  float d2v = dim [(bb*3 + 2)*HW + ind];
  float v0  = vel [(bb*2 + 0)*HW + ind];
  float v1  = vel [(bb*2 + 1)*HW + ind];
  float x = xs0 + r0, y = ys0 + r1;
  float rot = atan2f(sn, cs);
  float* bx = out + (size_t)t*9;
  bx[0]=x; bx[1]=y; bx[2]=he; bx[3]=d0; bx[4]=d1; bx[5]=d2v; bx[6]=rot; bx[7]=v0; bx[8]=v1;
  float scv = out[36000 + t];
  bool valid = (x >= -100.0f) && (x <= 1124.0f) &&
               (y >= -100.0f) && (y <= 1124.0f) &&
               (he >= -10.0f) && (he <= 10.0f) && (scv > 0.1f);
  out[44000 + t] = valid ? 1.0f : 0.0f;
}

// ---------------- K7: circle NMS (greedy, bitmask) ---------------------------
__global__ __launch_bounds__(512) void k7_nms(float* out){
  int b = blockIdx.x;
  int t = threadIdx.x;
  __shared__ float xo[512], yo[512];
  __shared__ int vArr[512];
  __shared__ int sc[512];
  __shared__ int order[512];
  __shared__ float xs_s[512], ys_s[512];
  __shared__ u64 adj[512*8];    // 32 KiB
  __shared__ u64 keepw[8];

  float x = 0.f, y = 0.f; int v = 0;
  if (t < KTOP){
    const float* bx = out + (size_t)(b*KTOP + t)*9;
    x = bx[0]; y = bx[1];
    v = (out[44000 + b*KTOP + t] > 0.5f) ? 1 : 0;
  }
  xo[t] = x; yo[t] = y; vArr[t] = v; sc[t] = v;
  __syncthreads();
  // inclusive scan of valid flags (stable argsort == valid-first stable partition)
  for (int off = 1; off < 512; off <<= 1){
    int add = (t >= off) ? sc[t - off] : 0;
    __syncthreads();
    sc[t] += add;
    __syncthreads();
  }
  int nValid = sc[511];
  if (t < KTOP){
    int excl = sc[t] - vArr[t];
    int slot = vArr[t] ? excl : (nValid + (t - excl));
    order[slot] = t;
  }
  __syncthreads();
  if (t < KTOP){ int p = order[t]; xs_s[t] = xo[p]; ys_s[t] = yo[p]; }
  __syncthreads();
  // adjacency bitmask rows: adj[i][jc] bit l = (j=jc*64+l) > i && d2 <= thresh
  int wv = t >> 6, ln = t & 63;
  for (int i = wv; i < KTOP; i += 8){
    float xi = xs_s[i], yi = ys_s[i];
    #pragma unroll
    for (int jc = 0; jc < 8; ++jc){
      int j = jc*64 + ln;
      bool pred = false;
      if (j < KTOP && j > i){
        float dx = __fsub_rn(xs_s[j], xi);
        float dy = __fsub_rn(ys_s[j], yi);
        float d2 = __fadd_rn(__fmul_rn(dx,dx), __fmul_rn(dy,dy));
        pred = (d2 <= 4.0f);
      }
      u64 m = __ballot(pred);
      if (ln == 0) adj[i*8 + jc] = m;
    }
  }
  __syncthreads();
  // sequential greedy suppression: 8 lanes own one 64-bit supp word each
  if (t < 64){
    u64 supp = 0ull;
    for (int i = 0; i < KTOP; ++i){
      u64 row = adj[i*8 + (t & 7)];
      if (t >= 8) row = 0ull;
      u64 w = __shfl(supp, i >> 6);
      if (!((w >> (i & 63)) & 1ull)) supp |= row;
    }
    if (t < 8){
      u64 kp = ~supp;
      if (t == 7) kp &= ((1ull << 52) - 1ull);  // j in [448,500)
      keepw[t] = kp;
    }
  }
  __syncthreads();
  // cumsum cap at POST_MAX
  if (t == 0){
    int budget = POST_MAX;
    for (int c2 = 0; c2 < 8; ++c2){
      u64 w = keepw[c2];
      int n = __popcll(w);
      if (n <= budget){ budget -= n; }
      else {
        while (n > budget){ w &= ~(1ull << (63 - __clzll(w))); --n; }
        budget = 0;
      }
      keepw[c2] = w;
    }
  }
  __syncthreads();
  if (t < KTOP){
    int bit = (int)((keepw[t >> 6] >> (t & 63)) & 1ull);
    int p = order[t];
    out[48000 + b*KTOP + p] = (bit && vArr[p]) ? 1.0f : 0.0f;
  }
}

extern "C" void kernel_launch(void* const* d_in, const int* in_sizes, int n_in,
                              void* d_out, int out_size, void* d_ws, size_t ws_size,
                              hipStream_t stream){
  const float* heat = (const float*)d_in[0];
  const float* reg  = (const float*)d_in[1];
  const float* rots = (const float*)d_in[2];
  const float* rotc = (const float*)d_in[3];
  const float* hei  = (const float*)d_in[4];
  const float* dim  = (const float*)d_in[5];
  const float* vel  = (const float*)d_in[6];
  float* out = (float*)d_out;
  char* ws = (char*)d_ws;
  u32*   cnt   = (u32*)  (ws + WS_CNT);
  u32*   flag  = (u32*)  (ws + WS_FLAG);
  u32*   tc2   = (u32*)  (ws + WS_TC2);
  u32*   ghist = (u32*)  (ws + WS_HIST);
  uint2* cand  = (uint2*)(ws + WS_CAND);
  uint2* s1    = (uint2*)(ws + WS_S1);
  u32*   sel   = (u32*)  (ws + WS_SEL);

  hipMemsetAsync(ws, 0, 16640, stream);                       // cnt + flag + tc2 + hist
  k1_collect <<<1024, 256, 0, stream>>>(heat, cnt, ghist, cand);
  k2_flags   <<<1,    64,  0, stream>>>(cnt, flag, tc2, ghist);
  k3_fallback<<<1024, 256, 0, stream>>>(heat, cnt, flag, tc2, cand);
  k4_sort    <<<16,   512, 0, stream>>>(cnt, cand, s1);
  k5_merge   <<<8,    512, 0, stream>>>(s1, sel, out);
  k6_decode  <<<16,   256, 0, stream>>>(reg, rots, rotc, hei, dim, vel, sel, out);
  k7_nms     <<<8,    512, 0, stream>>>(out);
}

// Round 2
// 350.054 us; speedup vs baseline: 1.0404x; 1.0404x over previous
//
#include <hip/hip_runtime.h>
#include <stdint.h>

typedef unsigned int u32;
typedef unsigned long long u64;

#define HW (1024*1024)
#define NSLICE 16
#define BATCH 8
#define KTOP 500
#define CAP 8192u
#define POST_MAX 83

// workspace byte offsets
#define WS_CNT   0          // u32[16]
#define WS_FLAG  64         // u32[16]
#define WS_HIST  256        // u32[16*256] -> ends 16640
#define WS_CAND  32768      // uint2[16*8192] -> 1 MiB
#define WS_S1    1081344    // uint2[16*512]

// out layout (floats): boxes[0,36000) scores[36000,40000) clses[40000,44000)
// valid[44000,48000) keep[48000,52000)

// ---------------- K1: pure streaming collect (static ulp threshold) ----------
__global__ __launch_bounds__(256) void k1_collect(const float* __restrict__ heat,
                                                  u32* cnt, uint2* cand){
  int s     = blockIdx.x >> 6;   // 16 slices x 64 chunks
  int chunk = blockIdx.x & 63;
  int tid   = threadIdx.x;
  const float4* hp = (const float4*)(heat + (size_t)s*HW + (size_t)chunk*16384);
  u32 base_pos = (u32)chunk * 16384u;
  for (int it = 0; it < 16; ++it){
    float4 v = hp[it*256 + tid];
    u32 idx0 = base_pos + (u32)(it*256 + tid)*4u;
    #pragma unroll
    for (int c = 0; c < 4; ++c){
      float val = (c==0)?v.x:(c==1)?v.y:(c==2)?v.z:v.w;
      u32 bits  = __float_as_uint(val);
      u32 delta = 0x3F800000u - bits;         // ulps below 1.0 (underflows for v>1/neg)
      if (delta < 17408u){                    // v > 1 - 17408*2^-24 ~ 0.998963
        u32 pos = atomicAdd(&cnt[s], 1u);
        if (pos < CAP) cand[(size_t)s*CAP + pos] = make_uint2(bits, idx0 + (u32)c);
      }
    }
  }
}

// ---------------- K2: exactness flag --------------------------------------
__global__ void k2_flags(u32* cnt, u32* flag){
  int s = threadIdx.x;
  if (s >= NSLICE) return;
  if (cnt[s] >= (u32)KTOP){
    flag[s] = 1u;
  } else {
    flag[s] = 0u;
    cnt[s] = 0u;     // k3 recollects from scratch
  }
}

// ---------------- K_hist: fallback histogram (early-exit normally) -----------
__global__ __launch_bounds__(256) void k_hist(const float* __restrict__ heat,
                                              const u32* __restrict__ flag, u32* ghist){
  int s = blockIdx.x >> 4;       // 16 slices x 16 chunks
  if (flag[s]) return;
  int chunk = blockIdx.x & 15;
  int tid = threadIdx.x;
  __shared__ u32 lhist[256];
  lhist[tid] = 0;
  __syncthreads();
  const float4* hp = (const float4*)(heat + (size_t)s*HW + (size_t)chunk*65536);
  for (int it = 0; it < 64; ++it){
    float4 v = hp[it*256 + tid];
    #pragma unroll
    for (int c = 0; c < 4; ++c){
      float val = (c==0)?v.x:(c==1)?v.y:(c==2)?v.z:v.w;
      u32 bits  = __float_as_uint(val);
      u32 delta = 0x3F800000u - bits;
      u32 bin   = delta >> 16; if (bin > 255u) bin = 255u;
      atomicAdd(&lhist[bin], 1u);
    }
  }
  __syncthreads();
  atomicAdd(&ghist[s*256 + tid], lhist[tid]);
}

// ---------------- K3: fallback exact collect (early-exit normally) -----------
__global__ __launch_bounds__(256) void k3_fallback(const float* __restrict__ heat,
                                                   u32* cnt, const u32* __restrict__ flag,
                                                   const u32* __restrict__ ghist, uint2* cand){
  int s = blockIdx.x >> 4;
  if (flag[s]) return;
  int chunk = blockIdx.x & 15;
  int tid = threadIdx.x;
  __shared__ int t2s;
  if (tid == 0){
    u32 cum = 0; u32 b1 = 255u;
    for (u32 bb = 0; bb < 256u; ++bb){
      cum += ghist[s*256 + (int)bb];
      if (cum >= (u32)KTOP){ b1 = bb; break; }
    }
    t2s = (int)(0x3F800000u - ((b1 + 1u) << 16) + 1u);
  }
  __syncthreads();
  int t2 = t2s;
  const float4* hp = (const float4*)(heat + (size_t)s*HW + (size_t)chunk*65536);
  u32 base_pos = (u32)chunk * 65536u;
  for (int it = 0; it < 64; ++it){
    float4 v = hp[it*256 + tid];
    u32 idx0 = base_pos + (u32)(it*256 + tid)*4u;
    #pragma unroll
    for (int c = 0; c < 4; ++c){
      float val = (c==0)?v.x:(c==1)?v.y:(c==2)?v.z:v.w;
      int bits = (int)__float_as_uint(val);   // signed cmp excludes negatives
      if (bits >= t2){
        u32 pos = atomicAdd(&cnt[s], 1u);
        if (pos < CAP) cand[(size_t)s*CAP + pos] = make_uint2((u32)bits, idx0 + (u32)c);
      }
    }
  }
}

// ---------------- bitonic sort (ascending, u64 keys in LDS) -----------------
__device__ inline void bitonic_sort(u64* key, int N, int tid, int nthr){
  for (int len = 2; len <= N; len <<= 1){
    for (int stride = len >> 1; stride > 0; stride >>= 1){
      __syncthreads();
      for (int i = tid; i < N; i += nthr){
        int j = i ^ stride;
        if (j > i){
          u64 a = key[i], b = key[j];
          bool up = ((i & len) == 0);
          if ((a > b) == up){ key[i] = b; key[j] = a; }
        }
      }
    }
  }
  __syncthreads();
}

// ---------------- K4: per-slice exact top-500 --------------------------------
__global__ __launch_bounds__(1024) void k4_sort(const u32* __restrict__ cnt,
                                                const uint2* __restrict__ cand, uint2* s1){
  __shared__ u64 key[8192];   // 64 KiB
  int s = blockIdx.x, tid = threadIdx.x;
  u32 n = cnt[s]; if (n > CAP) n = CAP;
  int Np = 1024; while (Np < (int)n) Np <<= 1;
  for (int i = tid; i < Np; i += 1024){
    u64 k = ~0ull;
    if (i < (int)n){
      uint2 cv = cand[(size_t)s*CAP + i];
      k = ((u64)(~cv.x) << 32) | (u64)cv.y;   // value desc, index asc
    }
    key[i] = k;
  }
  bitonic_sort(key, Np, tid, 1024);
  if (tid < KTOP){
    u64 k = key[tid];
    s1[s*512 + tid] = make_uint2(~(u32)(k >> 32), (u32)(k & 0xFFFFFFFFull));
  }
}

// ---------------- K5: fused merge + decode + circle NMS ----------------------
__global__ __launch_bounds__(512) void k5_fused(const uint2* __restrict__ s1,
                                                const float* __restrict__ reg,
                                                const float* __restrict__ rots,
                                                const float* __restrict__ rotc,
                                                const float* __restrict__ hei,
                                                const float* __restrict__ dim,
                                                const float* __restrict__ vel,
                                                float* out){
  int b = blockIdx.x, t = threadIdx.x;
  __shared__ u64 adj[4096];          // 32 KiB; first 1024 reused as sort keys
  __shared__ float xo[512], yo[512];
  __shared__ float xs_s[512], ys_s[512];
  __shared__ int vArr[512], scn[512], order[512];
  __shared__ u64 keepw[8];
  u64* key = adj;

  // ---- phase 1: merge 2x500 -> top-500 (second lax.top_k, tie-break = c*K idx)
  for (int i = t; i < 1024; i += 512){
    u64 k = ~0ull;
    if (i < 2*KTOP){
      int c = (i >= KTOP) ? 1 : 0;
      int pos = i - c*KTOP;
      u32 bits = s1[(b*2 + c)*512 + pos].x;
      k = ((u64)(~bits) << 32) | (u64)i;
    }
    key[i] = k;
  }
  bitonic_sort(key, 1024, t, 512);
  u32 myind = 0; float mysc = 0.0f;
  if (t < KTOP){
    u64 k = key[t];
    u32 src = (u32)(k & 0xFFFFFFFFull);
    int c = (src >= (u32)KTOP) ? 1 : 0;
    int pos = (int)src - c*KTOP;
    u32 bits = ~(u32)(k >> 32);
    myind = s1[(b*2 + c)*512 + pos].y;
    mysc = __uint_as_float(bits);
    out[36000 + b*KTOP + t] = mysc;
    out[40000 + b*KTOP + t] = (float)c;
  }
  __syncthreads();

  // ---- phase 2: gather + decode + valid
  float x = 0.f, y = 0.f; int v = 0;
  if (t < KTOP){
    u32 ind = myind & (u32)(HW - 1);   // safety clamp
    float xs0 = (float)(ind & 1023u);
    float ys0 = (float)(ind >> 10);
    size_t bb = (size_t)b;
    float r0  = reg [(bb*2 + 0)*HW + ind];
    float r1  = reg [(bb*2 + 1)*HW + ind];
    float sn  = rots[ bb       *HW + ind];
    float cs  = rotc[ bb       *HW + ind];
    float he  = hei [ bb       *HW + ind];
    float d0  = dim [(bb*3 + 0)*HW + ind];
    float d1  = dim [(bb*3 + 1)*HW + ind];
    float d2v = dim [(bb*3 + 2)*HW + ind];
    float v0  = vel [(bb*2 + 0)*HW + ind];
    float v1  = vel [(bb*2 + 1)*HW + ind];
    x = xs0 + r0; y = ys0 + r1;
    float rot = atan2f(sn, cs);
    float* bx = out + (size_t)(b*KTOP + t)*9;
    bx[0]=x; bx[1]=y; bx[2]=he; bx[3]=d0; bx[4]=d1; bx[5]=d2v; bx[6]=rot; bx[7]=v0; bx[8]=v1;
    v = ((x >= -100.0f) && (x <= 1124.0f) &&
         (y >= -100.0f) && (y <= 1124.0f) &&
         (he >= -10.0f) && (he <= 10.0f) && (mysc > 0.1f)) ? 1 : 0;
    out[44000 + b*KTOP + t] = v ? 1.0f : 0.0f;
  }
  xo[t] = x; yo[t] = y; vArr[t] = v; scn[t] = v;
  __syncthreads();

  // ---- phase 3: stable valid-first partition (== argsort(-where(valid,s,-1e9)))
  for (int off = 1; off < 512; off <<= 1){
    int add = (t >= off) ? scn[t - off] : 0;
    __syncthreads();
    scn[t] += add;
    __syncthreads();
  }
  int nValid = scn[511];
  if (t < KTOP){
    int excl = scn[t] - vArr[t];
    int slot = vArr[t] ? excl : (nValid + (t - excl));
    order[slot] = t;
  }
  __syncthreads();
  if (t < KTOP){ int p = order[t]; xs_s[t] = xo[p]; ys_s[t] = yo[p]; }
  __syncthreads();

  // ---- phase 4: adjacency bitmask rows
  int wv = t >> 6, ln = t & 63;
  for (int i = wv; i < KTOP; i += 8){
    float xi = xs_s[i], yi = ys_s[i];
    #pragma unroll
    for (int jc = 0; jc < 8; ++jc){
      int j = jc*64 + ln;
      bool pred = false;
      if (j < KTOP && j > i){
        float dx = __fsub_rn(xs_s[j], xi);
        float dy = __fsub_rn(ys_s[j], yi);
        float d2 = __fadd_rn(__fmul_rn(dx,dx), __fmul_rn(dy,dy));
        pred = (d2 <= 4.0f);
      }
      u64 m = __ballot(pred);
      if (ln == 0) adj[i*8 + jc] = m;
    }
  }
  __syncthreads();

  // ---- phase 5: sequential greedy suppression (8 lanes own supp words)
  if (t < 64){
    u64 supp = 0ull;
    for (int i = 0; i < KTOP; ++i){
      u64 row = adj[i*8 + (t & 7)];
      if (t >= 8) row = 0ull;
      u64 w = __shfl(supp, i >> 6);
      if (!((w >> (i & 63)) & 1ull)) supp |= row;
    }
    if (t < 8){
      u64 kp = ~supp;
      if (t == 7) kp &= ((1ull << 52) - 1ull);  // j in [448,500)
      keepw[t] = kp;
    }
  }
  __syncthreads();

  // ---- phase 6: cumsum cap at POST_MAX
  if (t == 0){
    int budget = POST_MAX;
    for (int c2 = 0; c2 < 8; ++c2){
      u64 w = keepw[c2];
      int n = __popcll(w);
      if (n <= budget){ budget -= n; }
      else {
        while (n > budget){ w &= ~(1ull << (63 - __clzll(w))); --n; }
        budget = 0;
      }
      keepw[c2] = w;
    }
  }
  __syncthreads();
  if (t < KTOP){
    int bit = (int)((keepw[t >> 6] >> (t & 63)) & 1ull);
    int p = order[t];
    out[48000 + b*KTOP + p] = (bit && vArr[p]) ? 1.0f : 0.0f;
  }
}

extern "C" void kernel_launch(void* const* d_in, const int* in_sizes, int n_in,
                              void* d_out, int out_size, void* d_ws, size_t ws_size,
                              hipStream_t stream){
  const float* heat = (const float*)d_in[0];
  const float* reg  = (const float*)d_in[1];
  const float* rots = (const float*)d_in[2];
  const float* rotc = (const float*)d_in[3];
  const float* hei  = (const float*)d_in[4];
  const float* dim  = (const float*)d_in[5];
  const float* vel  = (const float*)d_in[6];
  float* out = (float*)d_out;
  char* ws = (char*)d_ws;
  u32*   cnt   = (u32*)  (ws + WS_CNT);
  u32*   flag  = (u32*)  (ws + WS_FLAG);
  u32*   ghist = (u32*)  (ws + WS_HIST);
  uint2* cand  = (uint2*)(ws + WS_CAND);
  uint2* s1    = (uint2*)(ws + WS_S1);

  hipMemsetAsync(ws, 0, 16640, stream);   // cnt + flag + hist
  k1_collect <<<1024, 256, 0, stream>>>(heat, cnt, cand);
  k2_flags   <<<1,    64,  0, stream>>>(cnt, flag);
  k_hist     <<<256,  256, 0, stream>>>(heat, flag, ghist);
  k3_fallback<<<256,  256, 0, stream>>>(heat, cnt, flag, ghist, cand);
  k4_sort    <<<16,  1024, 0, stream>>>(cnt, cand, s1);
  k5_fused   <<<8,    512, 0, stream>>>(s1, reg, rots, rotc, hei, dim, vel, out);
}

// Round 3
// 172.970 us; speedup vs baseline: 2.1055x; 2.0238x over previous
//
#include <hip/hip_runtime.h>
#include <stdint.h>

typedef unsigned int u32;
typedef unsigned long long u64;

#define HW (1024*1024)
#define NSLICE 16
#define BATCH 8
#define KTOP 500
#define CAP 4096u
#define LCAP 1024u
#define POST_MAX 83

// workspace byte offsets
#define WS_CNT   0      // u32[16*16]  one counter per 64B line per slice
#define WS_FLAG  1024   // u32[16]
#define WS_DONE  1088   // u32[16]
#define WS_HIST  2048   // u32[16*256] -> ends 18432
#define WS_CAND  32768  // uint2[16*4096] = 512 KiB

// out layout (floats): boxes[0,36000) scores[36000,40000) clses[40000,44000)
// valid[44000,48000) keep[48000,52000)

// ---------------- K1: streaming collect, block-aggregated atomics ------------
__global__ __launch_bounds__(256) void k1_collect(const float* __restrict__ heat,
                                                  u32* cnt, u32* flag, u32* done,
                                                  uint2* cand){
  __shared__ uint2 lbuf[LCAP];
  __shared__ u32 lcnt, gbase;
  int s     = blockIdx.x >> 6;   // 16 slices x 64 chunks
  int chunk = blockIdx.x & 63;
  int tid   = threadIdx.x;
  if (tid == 0) lcnt = 0;
  __syncthreads();
  const float4* hp = (const float4*)(heat + (size_t)s*HW + (size_t)chunk*16384);
  u32 base_pos = (u32)chunk * 16384u;
  for (int it = 0; it < 16; ++it){
    float4 v = hp[it*256 + tid];
    u32 idx0 = base_pos + (u32)(it*256 + tid)*4u;
    #pragma unroll
    for (int c = 0; c < 4; ++c){
      float val = (c==0)?v.x:(c==1)?v.y:(c==2)?v.z:v.w;
      u32 bits  = __float_as_uint(val);
      u32 delta = 0x3F800000u - bits;         // ulps below 1.0
      if (delta < 17408u){                    // v > ~0.998963
        u32 p = atomicAdd(&lcnt, 1u);         // LDS atomic, rare
        if (p < LCAP) lbuf[p] = make_uint2(bits, idx0 + (u32)c);
        else {                                // overflow: direct global (never on this data)
          u32 gp = atomicAdd(&cnt[s*16], 1u);
          if (gp < CAP) cand[(size_t)s*CAP + gp] = make_uint2(bits, idx0 + (u32)c);
        }
      }
    }
  }
  __syncthreads();
  u32 n = (lcnt < LCAP) ? lcnt : LCAP;
  if (tid == 0) gbase = atomicAdd(&cnt[s*16], n);   // ONE global atomic per block
  __syncthreads();
  for (u32 i = tid; i < n; i += 256){
    u32 p = gbase + i;
    if (p < CAP) cand[(size_t)s*CAP + p] = lbuf[i];
  }
  __syncthreads();
  if (tid == 0){
    __threadfence();
    u32 d = atomicAdd(&done[s], 1u);
    if (d == 63u){                             // last block of slice: set exactness flag
      u32 c = atomicAdd(&cnt[s*16], 0u);       // coherent read
      if (c >= (u32)KTOP) flag[s] = 1u;
      else { flag[s] = 0u; cnt[s*16] = 0u; }   // fallback recollects
    }
  }
}

// ---------------- K_hist: fallback histogram (early-exit normally) -----------
__global__ __launch_bounds__(256) void k_hist(const float* __restrict__ heat,
                                              const u32* __restrict__ flag, u32* ghist){
  int s = blockIdx.x >> 4;       // 16 slices x 16 chunks
  if (flag[s]) return;
  int chunk = blockIdx.x & 15;
  int tid = threadIdx.x;
  __shared__ u32 lhist[256];
  lhist[tid] = 0;
  __syncthreads();
  const float4* hp = (const float4*)(heat + (size_t)s*HW + (size_t)chunk*65536);
  for (int it = 0; it < 64; ++it){
    float4 v = hp[it*256 + tid];
    #pragma unroll
    for (int c = 0; c < 4; ++c){
      float val = (c==0)?v.x:(c==1)?v.y:(c==2)?v.z:v.w;
      u32 bits  = __float_as_uint(val);
      u32 delta = 0x3F800000u - bits;
      u32 bin   = delta >> 16; if (bin > 255u) bin = 255u;
      atomicAdd(&lhist[bin], 1u);
    }
  }
  __syncthreads();
  atomicAdd(&ghist[s*256 + tid], lhist[tid]);
}

// ---------------- K3: fallback exact collect (early-exit normally) -----------
__global__ __launch_bounds__(256) void k3_fallback(const float* __restrict__ heat,
                                                   u32* cnt, const u32* __restrict__ flag,
                                                   const u32* __restrict__ ghist, uint2* cand){
  int s = blockIdx.x >> 4;
  if (flag[s]) return;
  int chunk = blockIdx.x & 15;
  int tid = threadIdx.x;
  __shared__ int t2s;
  if (tid == 0){
    u32 cum = 0; u32 b1 = 255u;
    for (u32 bb = 0; bb < 256u; ++bb){
      cum += ghist[s*256 + (int)bb];
      if (cum >= (u32)KTOP){ b1 = bb; break; }
    }
    t2s = (int)(0x3F800000u - ((b1 + 1u) << 16) + 1u);
  }
  __syncthreads();
  int t2 = t2s;
  const float4* hp = (const float4*)(heat + (size_t)s*HW + (size_t)chunk*65536);
  u32 base_pos = (u32)chunk * 65536u;
  for (int it = 0; it < 64; ++it){
    float4 v = hp[it*256 + tid];
    u32 idx0 = base_pos + (u32)(it*256 + tid)*4u;
    #pragma unroll
    for (int c = 0; c < 4; ++c){
      float val = (c==0)?v.x:(c==1)?v.y:(c==2)?v.z:v.w;
      int bits = (int)__float_as_uint(val);   // signed cmp excludes negatives
      if (bits >= t2){
        u32 pos = atomicAdd(&cnt[s*16], 1u);
        if (pos < CAP) cand[(size_t)s*CAP + pos] = make_uint2((u32)bits, idx0 + (u32)c);
      }
    }
  }
}

// ---------------- K45: dual-sort + merge + decode + circle NMS ---------------
__global__ __launch_bounds__(1024) void k45_fused(const u32* __restrict__ cnt,
                                                  const uint2* __restrict__ cand,
                                                  const float* __restrict__ reg,
                                                  const float* __restrict__ rots,
                                                  const float* __restrict__ rotc,
                                                  const float* __restrict__ hei,
                                                  const float* __restrict__ dim,
                                                  const float* __restrict__ vel,
                                                  float* out){
  __shared__ u64 key[8192];          // 64 KiB; adj aliases first 32 KiB later
  __shared__ uint2 topv[2][512];
  __shared__ float xo[512], yo[512], xs_s[512], ys_s[512];
  __shared__ int vArr[512], scn[512], order[512];
  __shared__ u64 keepw[8];
  u64* adj = key;

  int b = blockIdx.x, t = threadIdx.x;
  int s0 = 2*b, s1v = 2*b + 1;
  u32 n0 = cnt[s0*16];  if (n0 > CAP) n0 = CAP;
  u32 n1 = cnt[s1v*16]; if (n1 > CAP) n1 = CAP;
  u32 nmax = (n0 > n1) ? n0 : n1;
  int NP = 1024; while (NP < (int)nmax) NP <<= 1;   // <= 4096

  // ---- load both slices' candidates (keyed: value desc, heat-idx asc)
  for (int i = t; i < 2*NP; i += 1024){
    int seg = (i >= NP) ? 1 : 0;
    int ii  = i & (NP - 1);
    u32 n   = seg ? n1 : n0;
    int s   = seg ? s1v : s0;
    u64 k = ~0ull;
    if (ii < (int)n){
      uint2 cv = cand[(size_t)s*CAP + ii];
      k = ((u64)(~cv.x) << 32) | (u64)cv.y;
    }
    key[i] = k;
  }
  // ---- dual independent bitonic sorts (same network, two segments)
  for (int len = 2; len <= NP; len <<= 1){
    for (int stride = len >> 1; stride > 0; stride >>= 1){
      __syncthreads();
      for (int i = t; i < 2*NP; i += 1024){
        int base = i & ~(NP - 1);
        int ii   = i & (NP - 1);
        int jj   = ii ^ stride;
        if (jj > ii){
          u64 a = key[base + ii], bb = key[base + jj];
          bool up = ((ii & len) == 0);
          if ((a > bb) == up){ key[base + ii] = bb; key[base + jj] = a; }
        }
      }
    }
  }
  __syncthreads();
  if (t < 512){
    u64 k0 = key[t];
    u64 k1 = key[NP + t];
    topv[0][t] = make_uint2(~(u32)(k0 >> 32), (u32)k0);
    topv[1][t] = make_uint2(~(u32)(k1 >> 32), (u32)k1);
  }
  __syncthreads();

  // ---- 10-pass bitonic merge of the two sorted 500-lists
  // key layout: [0,512) = list0 ascending (pad ~0), [512,1024) = list1 descending
  {
    u64 k;
    if (t < 512){
      k = (t < KTOP) ? (((u64)(~topv[0][t].x) << 32) | (u64)t) : ~0ull;
    } else {
      int p = 511 - (t - 512);
      k = (p < KTOP) ? (((u64)(~topv[1][p].x) << 32) | (u64)(KTOP + p)) : ~0ull;
    }
    key[t] = k;
  }
  for (int stride = 512; stride > 0; stride >>= 1){
    __syncthreads();
    int j = t ^ stride;
    if (j > t){
      u64 a = key[t], bb = key[j];
      if (a > bb){ key[t] = bb; key[j] = a; }
    }
  }
  __syncthreads();

  u32 myind = 0; float mysc = 0.0f;
  if (t < KTOP){
    u64 k = key[t];
    u32 src = (u32)k;                 // position in concatenated c*K array
    int c = (src >= (u32)KTOP) ? 1 : 0;
    int pos = (int)src - c*KTOP;
    myind = topv[c][pos].y;
    mysc = __uint_as_float(~(u32)(k >> 32));
    out[36000 + b*KTOP + t] = mysc;
    out[40000 + b*KTOP + t] = (float)c;
  }
  __syncthreads();

  // ---- gather + decode + valid
  float x = 0.f, y = 0.f; int v = 0;
  if (t < KTOP){
    u32 ind = myind & (u32)(HW - 1);
    float xs0 = (float)(ind & 1023u);
    float ys0 = (float)(ind >> 10);
    size_t bb = (size_t)b;
    float r0  = reg [(bb*2 + 0)*HW + ind];
    float r1  = reg [(bb*2 + 1)*HW + ind];
    float sn  = rots[ bb       *HW + ind];
    float cs  = rotc[ bb       *HW + ind];
    float he  = hei [ bb       *HW + ind];
    float d0  = dim [(bb*3 + 0)*HW + ind];
    float d1  = dim [(bb*3 + 1)*HW + ind];
    float d2v = dim [(bb*3 + 2)*HW + ind];
    float v0  = vel [(bb*2 + 0)*HW + ind];
    float v1  = vel [(bb*2 + 1)*HW + ind];
    x = xs0 + r0; y = ys0 + r1;
    float rot = atan2f(sn, cs);
    float* bx = out + (size_t)(b*KTOP + t)*9;
    bx[0]=x; bx[1]=y; bx[2]=he; bx[3]=d0; bx[4]=d1; bx[5]=d2v; bx[6]=rot; bx[7]=v0; bx[8]=v1;
    v = ((x >= -100.0f) && (x <= 1124.0f) &&
         (y >= -100.0f) && (y <= 1124.0f) &&
         (he >= -10.0f) && (he <= 10.0f) && (mysc > 0.1f)) ? 1 : 0;
    out[44000 + b*KTOP + t] = v ? 1.0f : 0.0f;
  }
  if (t < 512){ xo[t] = x; yo[t] = y; vArr[t] = v; scn[t] = v; }
  __syncthreads();

  // ---- stable valid-first partition (== argsort(-where(valid,s,-1e9)))
  for (int off = 1; off < 512; off <<= 1){
    int add = (t < 512 && t >= off) ? scn[t - off] : 0;
    __syncthreads();
    if (t < 512) scn[t] += add;
    __syncthreads();
  }
  int nValid = scn[511];
  if (t < KTOP){
    int excl = scn[t] - vArr[t];
    int slot = vArr[t] ? excl : (nValid + (t - excl));
    order[slot] = t;
  }
  __syncthreads();
  if (t < KTOP){ int p = order[t]; xs_s[t] = xo[p]; ys_s[t] = yo[p]; }
  __syncthreads();

  // ---- adjacency bitmask rows (16 waves)
  int wv = t >> 6, ln = t & 63;
  for (int i = wv; i < KTOP; i += 16){
    float xi = xs_s[i], yi = ys_s[i];
    #pragma unroll
    for (int jc = 0; jc < 8; ++jc){
      int j = jc*64 + ln;
      bool pred = false;
      if (j < KTOP && j > i){
        float dx = __fsub_rn(xs_s[j], xi);
        float dy = __fsub_rn(ys_s[j], yi);
        float d2 = __fadd_rn(__fmul_rn(dx,dx), __fmul_rn(dy,dy));
        pred = (d2 <= 4.0f);
      }
      u64 m = __ballot(pred);
      if (ln == 0) adj[i*8 + jc] = m;
    }
  }
  __syncthreads();

  // ---- sequential greedy suppression (8 lanes own supp words)
  if (t < 64){
    u64 supp = 0ull;
    for (int i = 0; i < KTOP; ++i){
      u64 row = adj[i*8 + (t & 7)];
      if (t >= 8) row = 0ull;
      u64 w = __shfl(supp, i >> 6);
      if (!((w >> (i & 63)) & 1ull)) supp |= row;
    }
    if (t < 8){
      u64 kp = ~supp;
      if (t == 7) kp &= ((1ull << 52) - 1ull);  // j in [448,500)
      keepw[t] = kp;
    }
  }
  __syncthreads();

  // ---- cumsum cap at POST_MAX
  if (t == 0){
    int budget = POST_MAX;
    for (int c2 = 0; c2 < 8; ++c2){
      u64 w = keepw[c2];
      int n = __popcll(w);
      if (n <= budget){ budget -= n; }
      else {
        while (n > budget){ w &= ~(1ull << (63 - __clzll(w))); --n; }
        budget = 0;
      }
      keepw[c2] = w;
    }
  }
  __syncthreads();
  if (t < KTOP){
    int bit = (int)((keepw[t >> 6] >> (t & 63)) & 1ull);
    int p = order[t];
    out[48000 + b*KTOP + p] = (bit && vArr[p]) ? 1.0f : 0.0f;
  }
}

extern "C" void kernel_launch(void* const* d_in, const int* in_sizes, int n_in,
                              void* d_out, int out_size, void* d_ws, size_t ws_size,
                              hipStream_t stream){
  const float* heat = (const float*)d_in[0];
  const float* reg  = (const float*)d_in[1];
  const float* rots = (const float*)d_in[2];
  const float* rotc = (const float*)d_in[3];
  const float* hei  = (const float*)d_in[4];
  const float* dim  = (const float*)d_in[5];
  const float* vel  = (const float*)d_in[6];
  float* out = (float*)d_out;
  char* ws = (char*)d_ws;
  u32*   cnt   = (u32*)  (ws + WS_CNT);
  u32*   flag  = (u32*)  (ws + WS_FLAG);
  u32*   done  = (u32*)  (ws + WS_DONE);
  u32*   ghist = (u32*)  (ws + WS_HIST);
  uint2* cand  = (uint2*)(ws + WS_CAND);

  hipMemsetAsync(ws, 0, 18432, stream);   // cnt + flag + done + hist
  k1_collect <<<1024, 256, 0, stream>>>(heat, cnt, flag, done, cand);
  k_hist     <<<256,  256, 0, stream>>>(heat, flag, ghist);
  k3_fallback<<<256,  256, 0, stream>>>(heat, cnt, flag, ghist, cand);
  k45_fused  <<<8,   1024, 0, stream>>>(cnt, cand, reg, rots, rotc, hei, dim, vel, out);
}

// Round 4
// 156.165 us; speedup vs baseline: 2.3321x; 1.1076x over previous
//
#include <hip/hip_runtime.h>
#include <stdint.h>

typedef unsigned int u32;
typedef unsigned long long u64;

#define HW (1024*1024)
#define NSLICE 16
#define BATCH 8
#define KTOP 500
#define CAP 8192u
#define LCAP 256u
#define POST_MAX 83
#define DELTA_THR 9728u     // v > 1 - 9728*2^-24 ~ 0.99942; E[count/slice] ~ 580

// workspace byte offsets
#define WS_CNT   0          // u32[16*16]  one counter per 64B line per slice
#define WS_FLAG  1024       // u32[16]
#define WS_DONE  1088       // u32[16]
#define WS_HIST  2048       // u32[16*256] -> ends 18432
#define WS_CAND  32768      // uint2[16*8192] -> ends 1081344
#define WS_S1    1081344    // uint2[16*512] -> ends 1146880

// out layout (floats): boxes[0,36000) scores[36000,40000) clses[40000,44000)
// valid[44000,48000) keep[48000,52000)

// ---------------- K1: streaming collect, block-aggregated atomics ------------
__global__ __launch_bounds__(256) void k1_collect(const float* __restrict__ heat,
                                                  u32* cnt, u32* flag, u32* done,
                                                  uint2* cand){
  __shared__ uint2 lbuf[LCAP];
  __shared__ u32 lcnt, gbase;
  int s     = blockIdx.x >> 7;   // 16 slices x 128 chunks
  int chunk = blockIdx.x & 127;
  int tid   = threadIdx.x;
  if (tid == 0) lcnt = 0;
  __syncthreads();
  const float4* hp = (const float4*)(heat + (size_t)s*HW + (size_t)chunk*8192);
  u32 base_pos = (u32)chunk * 8192u;
  for (int it = 0; it < 8; ++it){
    float4 v = hp[it*256 + tid];
    u32 idx0 = base_pos + (u32)(it*256 + tid)*4u;
    #pragma unroll
    for (int c = 0; c < 4; ++c){
      float val = (c==0)?v.x:(c==1)?v.y:(c==2)?v.z:v.w;
      u32 bits  = __float_as_uint(val);
      u32 delta = 0x3F800000u - bits;         // ulps below 1.0
      if (delta < DELTA_THR){
        u32 p = atomicAdd(&lcnt, 1u);         // LDS atomic, rare (~5/block)
        if (p < LCAP) lbuf[p] = make_uint2(bits, idx0 + (u32)c);
        else {                                // overflow: direct global (never on this data)
          u32 gp = atomicAdd(&cnt[s*16], 1u);
          if (gp < CAP) cand[(size_t)s*CAP + gp] = make_uint2(bits, idx0 + (u32)c);
        }
      }
    }
  }
  __syncthreads();
  u32 n = (lcnt < LCAP) ? lcnt : LCAP;
  if (tid == 0) gbase = atomicAdd(&cnt[s*16], n);   // ONE global atomic per block
  __syncthreads();
  for (u32 i = tid; i < n; i += 256){
    u32 p = gbase + i;
    if (p < CAP) cand[(size_t)s*CAP + p] = lbuf[i];
  }
  __syncthreads();
  if (tid == 0){
    __threadfence();
    u32 d = atomicAdd(&done[s], 1u);
    if (d == 127u){                            // last block of slice
      u32 c = atomicAdd(&cnt[s*16], 0u);       // coherent read
      if (c >= (u32)KTOP) flag[s] = 1u;
      else { flag[s] = 0u; cnt[s*16] = 0u; }   // fallback recollects
    }
  }
}

// ---------------- K_hist: fallback histogram (early-exit normally) -----------
__global__ __launch_bounds__(256) void k_hist(const float* __restrict__ heat,
                                              const u32* __restrict__ flag, u32* ghist){
  int s = blockIdx.x >> 4;       // 16 slices x 16 chunks
  if (flag[s]) return;
  int chunk = blockIdx.x & 15;
  int tid = threadIdx.x;
  __shared__ u32 lhist[256];
  lhist[tid] = 0;
  __syncthreads();
  const float4* hp = (const float4*)(heat + (size_t)s*HW + (size_t)chunk*65536);
  for (int it = 0; it < 64; ++it){
    float4 v = hp[it*256 + tid];
    #pragma unroll
    for (int c = 0; c < 4; ++c){
      float val = (c==0)?v.x:(c==1)?v.y:(c==2)?v.z:v.w;
      u32 bits  = __float_as_uint(val);
      u32 delta = 0x3F800000u - bits;
      u32 bin   = delta >> 16; if (bin > 255u) bin = 255u;
      atomicAdd(&lhist[bin], 1u);
    }
  }
  __syncthreads();
  atomicAdd(&ghist[s*256 + tid], lhist[tid]);
}

// ---------------- K3: fallback exact collect (early-exit normally) -----------
__global__ __launch_bounds__(256) void k3_fallback(const float* __restrict__ heat,
                                                   u32* cnt, const u32* __restrict__ flag,
                                                   const u32* __restrict__ ghist, uint2* cand){
  int s = blockIdx.x >> 4;
  if (flag[s]) return;
  int chunk = blockIdx.x & 15;
  int tid = threadIdx.x;
  __shared__ int t2s;
  if (tid == 0){
    u32 cum = 0; u32 b1 = 255u;
    for (u32 bb = 0; bb < 256u; ++bb){
      cum += ghist[s*256 + (int)bb];
      if (cum >= (u32)KTOP){ b1 = bb; break; }
    }
    t2s = (int)(0x3F800000u - ((b1 + 1u) << 16) + 1u);
  }
  __syncthreads();
  int t2 = t2s;
  const float4* hp = (const float4*)(heat + (size_t)s*HW + (size_t)chunk*65536);
  u32 base_pos = (u32)chunk * 65536u;
  for (int it = 0; it < 64; ++it){
    float4 v = hp[it*256 + tid];
    u32 idx0 = base_pos + (u32)(it*256 + tid)*4u;
    #pragma unroll
    for (int c = 0; c < 4; ++c){
      float val = (c==0)?v.x:(c==1)?v.y:(c==2)?v.z:v.w;
      int bits = (int)__float_as_uint(val);   // signed cmp excludes negatives
      if (bits >= t2){
        u32 pos = atomicAdd(&cnt[s*16], 1u);
        if (pos < CAP) cand[(size_t)s*CAP + pos] = make_uint2((u32)bits, idx0 + (u32)c);
      }
    }
  }
}

// ---------------- bitonic sort (ascending, u64 keys in LDS) -----------------
__device__ inline void bitonic_sort(u64* key, int N, int tid, int nthr){
  for (int len = 2; len <= N; len <<= 1){
    for (int stride = len >> 1; stride > 0; stride >>= 1){
      __syncthreads();
      for (int i = tid; i < N; i += nthr){
        int j = i ^ stride;
        if (j > i){
          u64 a = key[i], b = key[j];
          bool up = ((i & len) == 0);
          if ((a > b) == up){ key[i] = b; key[j] = a; }
        }
      }
    }
  }
  __syncthreads();
}

// ---------------- KA: per-slice exact top-500 --------------------------------
__global__ __launch_bounds__(1024) void kA_sort(const u32* __restrict__ cnt,
                                                const uint2* __restrict__ cand, uint2* s1){
  __shared__ u64 key[8192];   // 64 KiB (large NP only on fallback path)
  int s = blockIdx.x, tid = threadIdx.x;
  u32 n = cnt[s*16]; if (n > CAP) n = CAP;
  int NP = 1024; while (NP < (int)n) NP <<= 1;
  for (int i = tid; i < NP; i += 1024){
    u64 k = ~0ull;
    if (i < (int)n){
      uint2 cv = cand[(size_t)s*CAP + i];
      k = ((u64)(~cv.x) << 32) | (u64)cv.y;   // value desc, index asc
    }
    key[i] = k;
  }
  bitonic_sort(key, NP, tid, 1024);
  if (tid < KTOP){
    u64 k = key[tid];
    s1[s*512 + tid] = make_uint2(~(u32)(k >> 32), (u32)(k & 0xFFFFFFFFull));
  }
}

// ---------------- KB: merge + decode + circle NMS ----------------------------
__global__ __launch_bounds__(1024) void kB_nms(const uint2* __restrict__ s1,
                                               const float* __restrict__ reg,
                                               const float* __restrict__ rots,
                                               const float* __restrict__ rotc,
                                               const float* __restrict__ hei,
                                               const float* __restrict__ dim,
                                               const float* __restrict__ vel,
                                               float* out){
  __shared__ u64 adj[4096];          // 32 KiB; first 1024 reused as merge keys
  __shared__ uint2 topv[2][512];
  __shared__ float xo[512], yo[512], xs_s[512], ys_s[512];
  __shared__ int vArr[512], scn[512], order[512];
  __shared__ u64 keepw[8];
  u64* key = adj;

  int b = blockIdx.x, t = threadIdx.x;

  // ---- load both sorted 500-lists
  if (t < 512)       topv[0][t] = s1[(b*2 + 0)*512 + t];
  else               topv[1][t-512] = s1[(b*2 + 1)*512 + (t-512)];
  __syncthreads();

  // ---- 10-pass bitonic merge (list0 asc, list1 desc; tie-break = c*K pos)
  if (t < 1024){
    u64 k;
    if (t < 512){
      k = (t < KTOP) ? (((u64)(~topv[0][t].x) << 32) | (u64)t) : ~0ull;
    } else {
      int p = 511 - (t - 512);
      k = (p < KTOP) ? (((u64)(~topv[1][p].x) << 32) | (u64)(KTOP + p)) : ~0ull;
    }
    key[t] = k;
  }
  for (int stride = 512; stride > 0; stride >>= 1){
    __syncthreads();
    int j = t ^ stride;
    if (t < 1024 && j > t){
      u64 a = key[t], bb = key[j];
      if (a > bb){ key[t] = bb; key[j] = a; }
    }
  }
  __syncthreads();

  u32 myind = 0; float mysc = 0.0f;
  if (t < KTOP){
    u64 k = key[t];
    u32 src = (u32)k;                 // position in concatenated c*K array
    int c = (src >= (u32)KTOP) ? 1 : 0;
    int pos = (int)src - c*KTOP;
    myind = topv[c][pos].y;
    mysc = __uint_as_float(~(u32)(k >> 32));
    out[36000 + b*KTOP + t] = mysc;
    out[40000 + b*KTOP + t] = (float)c;
  }
  __syncthreads();   // key (== adj) free after this point

  // ---- gather + decode + valid
  float x = 0.f, y = 0.f; int v = 0;
  if (t < KTOP){
    u32 ind = myind & (u32)(HW - 1);
    float xs0 = (float)(ind & 1023u);
    float ys0 = (float)(ind >> 10);
    size_t bb = (size_t)b;
    float r0  = reg [(bb*2 + 0)*HW + ind];
    float r1  = reg [(bb*2 + 1)*HW + ind];
    float sn  = rots[ bb       *HW + ind];
    float cs  = rotc[ bb       *HW + ind];
    float he  = hei [ bb       *HW + ind];
    float d0  = dim [(bb*3 + 0)*HW + ind];
    float d1  = dim [(bb*3 + 1)*HW + ind];
    float d2v = dim [(bb*3 + 2)*HW + ind];
    float v0  = vel [(bb*2 + 0)*HW + ind];
    float v1  = vel [(bb*2 + 1)*HW + ind];
    x = xs0 + r0; y = ys0 + r1;
    float rot = atan2f(sn, cs);
    float* bx = out + (size_t)(b*KTOP + t)*9;
    bx[0]=x; bx[1]=y; bx[2]=he; bx[3]=d0; bx[4]=d1; bx[5]=d2v; bx[6]=rot; bx[7]=v0; bx[8]=v1;
    v = ((x >= -100.0f) && (x <= 1124.0f) &&
         (y >= -100.0f) && (y <= 1124.0f) &&
         (he >= -10.0f) && (he <= 10.0f) && (mysc > 0.1f)) ? 1 : 0;
    out[44000 + b*KTOP + t] = v ? 1.0f : 0.0f;
  }
  if (t < 512){ xo[t] = x; yo[t] = y; vArr[t] = v; scn[t] = v; }
  __syncthreads();

  // ---- stable valid-first partition (== argsort(-where(valid,s,-1e9)))
  for (int off = 1; off < 512; off <<= 1){
    int add = (t < 512 && t >= off) ? scn[t - off] : 0;
    __syncthreads();
    if (t < 512) scn[t] += add;
    __syncthreads();
  }
  int nValid = scn[511];
  if (t < KTOP){
    int excl = scn[t] - vArr[t];
    int slot = vArr[t] ? excl : (nValid + (t - excl));
    order[slot] = t;
  }
  __syncthreads();
  if (t < KTOP){ int p = order[t]; xs_s[t] = xo[p]; ys_s[t] = yo[p]; }
  __syncthreads();

  // ---- adjacency bitmask rows (16 waves)
  int wv = t >> 6, ln = t & 63;
  for (int i = wv; i < KTOP; i += 16){
    float xi = xs_s[i], yi = ys_s[i];
    #pragma unroll
    for (int jc = 0; jc < 8; ++jc){
      int j = jc*64 + ln;
      bool pred = false;
      if (j < KTOP && j > i){
        float dx = __fsub_rn(xs_s[j], xi);
        float dy = __fsub_rn(ys_s[j], yi);
        float d2 = __fadd_rn(__fmul_rn(dx,dx), __fmul_rn(dy,dy));
        pred = (d2 <= 4.0f);
      }
      u64 m = __ballot(pred);
      if (ln == 0) adj[i*8 + jc] = m;
    }
  }
  __syncthreads();

  // ---- sequential greedy suppression: ballot-broadcast form
  // lanes 0..7 own 64-bit supp words; owner lane tests bit i, ballot broadcasts.
  if (t < 64){
    u64 supp = 0ull;
    for (int i = 0; i < KTOP; ++i){
      u64 row = adj[i*8 + (t & 7)];
      if (t >= 8) row = 0ull;
      bool sup_i = false;
      if (t == (i >> 6)) sup_i = ((supp >> (i & 63)) & 1ull) != 0ull;
      u64 m = __ballot(sup_i);
      if (m == 0ull) supp |= row;       // wave-uniform branch
    }
    if (t < 8){
      u64 kp = ~supp;
      if (t == 7) kp &= ((1ull << 52) - 1ull);  // j in [448,500)
      keepw[t] = kp;
    }
  }
  __syncthreads();

  // ---- cumsum cap at POST_MAX
  if (t == 0){
    int budget = POST_MAX;
    for (int c2 = 0; c2 < 8; ++c2){
      u64 w = keepw[c2];
      int n = __popcll(w);
      if (n <= budget){ budget -= n; }
      else {
        while (n > budget){ w &= ~(1ull << (63 - __clzll(w))); --n; }
        budget = 0;
      }
      keepw[c2] = w;
    }
  }
  __syncthreads();
  if (t < KTOP){
    int bit = (int)((keepw[t >> 6] >> (t & 63)) & 1ull);
    int p = order[t];
    out[48000 + b*KTOP + p] = (bit && vArr[p]) ? 1.0f : 0.0f;
  }
}

extern "C" void kernel_launch(void* const* d_in, const int* in_sizes, int n_in,
                              void* d_out, int out_size, void* d_ws, size_t ws_size,
                              hipStream_t stream){
  const float* heat = (const float*)d_in[0];
  const float* reg  = (const float*)d_in[1];
  const float* rots = (const float*)d_in[2];
  const float* rotc = (const float*)d_in[3];
  const float* hei  = (const float*)d_in[4];
  const float* dim  = (const float*)d_in[5];
  const float* vel  = (const float*)d_in[6];
  float* out = (float*)d_out;
  char* ws = (char*)d_ws;
  u32*   cnt   = (u32*)  (ws + WS_CNT);
  u32*   flag  = (u32*)  (ws + WS_FLAG);
  u32*   done  = (u32*)  (ws + WS_DONE);
  u32*   ghist = (u32*)  (ws + WS_HIST);
  uint2* cand  = (uint2*)(ws + WS_CAND);
  uint2* s1    = (uint2*)(ws + WS_S1);

  hipMemsetAsync(ws, 0, 18432, stream);   // cnt + flag + done + hist
  k1_collect <<<2048, 256, 0, stream>>>(heat, cnt, flag, done, cand);
  k_hist     <<<256,  256, 0, stream>>>(heat, flag, ghist);
  k3_fallback<<<256,  256, 0, stream>>>(heat, cnt, flag, ghist, cand);
  kA_sort    <<<16,  1024, 0, stream>>>(cnt, cand, s1);
  kB_nms     <<<8,   1024, 0, stream>>>(s1, reg, rots, rotc, hei, dim, vel, out);
}